// Round 3
// baseline (186.178 us; speedup 1.0000x reference)
//
#include <hip/hip_runtime.h>
#include <math.h>

// Network_22892175688023 — round 3: fragment-order global planes, LDS-free MFMA gens.
//
//   prep    : x, ew1, ew2, ew3 -> bf16 hi/lo planes in MFMA fragment order
//   enc_pre : h1raw = xs@w1^T + b1 + column stats
//   enc_mid : h2raw = relu(bn1(h1raw))@w2^T + b2 + stats2
//   gate    : latent=relu(bn2); gating MLP -> bc[1024,8]
//   gen1    : p[e] = xs @ ew1_e     (wave-per-64x64-tile, direct-from-global fragments)
//   combine : a = elu(sum_e bc_e*(p[e]+eb1_e)) -> fragment-order bf16 hi/lo planes
//   gen2    : p[e] = a @ ew2_e
//   combine : a = elu(sum_e bc_e*(p[e]+eb2_e))
//   gen3    : p3[e] = a @ ew3_e  (N=51 pad 64)
//   combine3: out = sum_e bc_e*(p3[e]+eb3_e)
//
// Fragment order: element (r,k) of a 32-wide K-chunk lives at short index
//   (subtile)*512 + l*8 + j,  l = ((k&31)>>3)*16 + (r&15), j = k&7
// so lane l of a wave reads its whole 8-bf16 MFMA fragment as one b128 at l*16 B.

#define DIN 103
#define L1W 64
#define L2W 32
#define NE  8
#define GH  64
#define HH  256
#define DOUT 51
#define EPSBN 1e-5f

typedef __attribute__((ext_vector_type(8))) short bf16x8;
typedef __attribute__((ext_vector_type(4))) float f32x4;
typedef __attribute__((ext_vector_type(8))) unsigned short us8;

__device__ __forceinline__ float eluf(float v) { return v > 0.f ? v : (expf(v) - 1.f); }

__device__ __forceinline__ unsigned short bf16h(float f) {
  unsigned u = __float_as_uint(f);
  u += 0x7FFFu + ((u >> 16) & 1u);
  return (unsigned short)(u >> 16);
}
__device__ __forceinline__ float bf16f(unsigned short h) {
  return __uint_as_float(((unsigned)h) << 16);
}
__device__ __forceinline__ void split_bf16(float v, unsigned short& h, unsigned short& l) {
  h = bf16h(v);
  l = bf16h(v - bf16f(h));
}

// ---------------- ws layout (float offsets) ----------------
// h1raw 0 (65536) | h2raw 65536 (32768) | bc 98304 (8192) | stats 106496 (192)
// XsH 106752 (65536) | XsL 172288 (65536)
// E1H 237824 (131072) | E1L 368896 (131072)
// E2H 499968 (262144) | E2L 762112 (262144)
// E3H 1024256 (65536) | E3L 1089792 (65536)
// AH 1155328 (131072) | AL 1286400 (131072)
// p 1417472 (2097152)  [8][1024][256]; reused as p3 [8][1024][64]

// =============== prep: all operands -> fragment-order bf16 hi/lo ===============
// sections (gid): x 16384 | ew1 32768 | ew2 65536 | ew3 16384  => 131072 threads
__global__ __launch_bounds__(256) void prep(const float* __restrict__ x,
    const float* __restrict__ ew1, const float* __restrict__ ew2, const float* __restrict__ ew3,
    unsigned short* __restrict__ XsH, unsigned short* __restrict__ XsL,
    unsigned short* __restrict__ E1H, unsigned short* __restrict__ E1L,
    unsigned short* __restrict__ E2H, unsigned short* __restrict__ E2L,
    unsigned short* __restrict__ E3H, unsigned short* __restrict__ E3L) {
  int gid = blockIdx.x * 256 + threadIdx.x;
  us8 H, L;
  if (gid < 16384) {                       // x: [64 msub][4 kc][64 l]
    int g = gid;
    int l = g & 63, kc = (g >> 6) & 3, msub = g >> 8;
    int b = msub * 16 + (l & 15);
    int k0 = kc * 32 + (l >> 4) * 8;
#pragma unroll
    for (int j = 0; j < 8; ++j) {
      int k = k0 + j;
      float v = 0.f;
      if (k < DIN) { v = x[(size_t)b * DIN + k]; if (k >= 100) v *= 100.f; }
      unsigned short h, lo; split_bf16(v, h, lo); H[j] = h; L[j] = lo;
    }
    *(us8*)(XsH + (size_t)g * 8) = H; *(us8*)(XsL + (size_t)g * 8) = L;
  } else if (gid < 49152) {                // ew1: [8 e][16 nsub][4 kc][64 l]
    int g = gid - 16384;
    int l = g & 63, kc = (g >> 6) & 3, nsub = (g >> 8) & 15, e = g >> 12;
    int n = nsub * 16 + (l & 15);
    int k0 = kc * 32 + (l >> 4) * 8;
#pragma unroll
    for (int j = 0; j < 8; ++j) {
      int k = k0 + j;
      float v = (k < DIN) ? ew1[((size_t)e * DIN + k) * HH + n] : 0.f;
      unsigned short h, lo; split_bf16(v, h, lo); H[j] = h; L[j] = lo;
    }
    *(us8*)(E1H + (size_t)g * 8) = H; *(us8*)(E1L + (size_t)g * 8) = L;
  } else if (gid < 114688) {               // ew2: [8 e][16 nsub][8 kc][64 l]
    int g = gid - 49152;
    int l = g & 63, kc = (g >> 6) & 7, nsub = (g >> 9) & 15, e = g >> 13;
    int n = nsub * 16 + (l & 15);
    int k0 = kc * 32 + (l >> 4) * 8;
#pragma unroll
    for (int j = 0; j < 8; ++j) {
      int k = k0 + j;
      float v = ew2[((size_t)e * HH + k) * HH + n];
      unsigned short h, lo; split_bf16(v, h, lo); H[j] = h; L[j] = lo;
    }
    *(us8*)(E2H + (size_t)g * 8) = H; *(us8*)(E2L + (size_t)g * 8) = L;
  } else {                                 // ew3: [8 e][4 nsub][8 kc][64 l], N pad 51->64
    int g = gid - 114688;
    int l = g & 63, kc = (g >> 6) & 7, nsub = (g >> 9) & 3, e = g >> 11;
    int n = nsub * 16 + (l & 15);
    int k0 = kc * 32 + (l >> 4) * 8;
#pragma unroll
    for (int j = 0; j < 8; ++j) {
      int k = k0 + j;
      float v = (n < DOUT) ? ew3[((size_t)e * HH + k) * DOUT + n] : 0.f;
      unsigned short h, lo; split_bf16(v, h, lo); H[j] = h; L[j] = lo;
    }
    *(us8*)(E3H + (size_t)g * 8) = H; *(us8*)(E3L + (size_t)g * 8) = L;
  }
}

// =============== encoder layer 1 + stats ===============
__global__ __launch_bounds__(256) void enc_pre(const float* __restrict__ x,
    const float* __restrict__ w1, const float* __restrict__ b1,
    float* __restrict__ h1raw, float* __restrict__ stats) {
  __shared__ float w1L[DIN * L1W];
  __shared__ float lsum[L1W], lsq[L1W];
  int t = threadIdx.x;
  for (int idx = t; idx < DIN * L1W; idx += 256) w1L[idx] = w1[idx];
  if (t < L1W) { lsum[t] = 0.f; lsq[t] = 0.f; }
  __syncthreads();
  int wave = t >> 6, j = t & 63;
  int row = blockIdx.x * 4 + wave;
  const float* xr = x + row * DIN;
  float acc = b1[j];
  for (int i = 0; i < DIN; ++i) {
    float xv = xr[i];
    if (i >= 100) xv *= 100.f;
    acc = fmaf(xv, w1L[j * DIN + i], acc);
  }
  h1raw[row * L1W + j] = acc;
  atomicAdd(&lsum[j], acc);
  atomicAdd(&lsq[j], acc * acc);
  __syncthreads();
  if (t < L1W) { atomicAdd(&stats[t], lsum[t]); atomicAdd(&stats[64 + t], lsq[t]); }
}

// =============== bn1+relu, encoder layer 2 + stats2 ===============
__global__ __launch_bounds__(256) void enc_mid(const float* __restrict__ h1raw,
    const float* __restrict__ stats, const float* __restrict__ gamma1, const float* __restrict__ beta1,
    const float* __restrict__ w2, const float* __restrict__ b2,
    float* __restrict__ h2raw, float* __restrict__ stats2) {
  __shared__ float w2L[L1W * 33];
  __shared__ float sc1[L1W], sh1[L1W];
  __shared__ float ls[L2W], lq[L2W];
  int t = threadIdx.x;
  for (int idx = t; idx < L1W * L2W; idx += 256) {
    int j = idx & 31, k = idx >> 5;
    w2L[k * 33 + j] = w2[j * L1W + k];
  }
  if (t < L1W) {
    float m = stats[t] * (1.f / 1024.f);
    float v = stats[64 + t] * (1.f / 1024.f) - m * m;
    float sc = gamma1[t] * rsqrtf(v + EPSBN);
    sc1[t] = sc; sh1[t] = beta1[t] - m * sc;
  }
  if (t < L2W) { ls[t] = 0.f; lq[t] = 0.f; }
  __syncthreads();
  int wave = t >> 6, l = t & 63;
  int j = l & 31, kh = l >> 5;
  int row = blockIdx.x * 4 + wave;
  const float* hr = h1raw + row * L1W;
  float acc = 0.f;
  for (int kk = 0; kk < 32; ++kk) {
    int k = kh * 32 + kk;
    float xv = fmaxf(fmaf(hr[k], sc1[k], sh1[k]), 0.f);
    acc = fmaf(xv, w2L[k * 33 + j], acc);
  }
  float tot = acc + __shfl_xor(acc, 32);
  if (kh == 0) {
    tot += b2[j];
    h2raw[row * L2W + j] = tot;
    atomicAdd(&ls[j], tot);
    atomicAdd(&lq[j], tot * tot);
  }
  __syncthreads();
  if (t < L2W) { atomicAdd(&stats2[t], ls[t]); atomicAdd(&stats2[32 + t], lq[t]); }
}

// =============== bn2+relu, gating MLP -> bc ===============
__global__ __launch_bounds__(256) void gate_kernel(
    const float* __restrict__ h2raw, const float* __restrict__ stats2,
    const float* __restrict__ gamma2, const float* __restrict__ beta2,
    const float* __restrict__ gw1, const float* __restrict__ gb1,
    const float* __restrict__ gw2, const float* __restrict__ gb2,
    const float* __restrict__ gw3, const float* __restrict__ gb3,
    float* __restrict__ bc) {
  __shared__ float gw1L[GH * 33];
  __shared__ float gw2L[GH * 65];
  __shared__ float gw3L[NE * 65];
  __shared__ float sc2[L2W], sh2[L2W];
  __shared__ float gb1L[GH], gb2L[GH], gb3L[NE];
  __shared__ float latb[4][L2W], g1b[4][GH], g2b[4][GH], lgb[4][NE];
  int t = threadIdx.x;
  for (int idx = t; idx < GH * L2W; idx += 256) { int jj = idx >> 5, kk = idx & 31; gw1L[jj * 33 + kk] = gw1[idx]; }
  for (int idx = t; idx < GH * GH;  idx += 256) { int jj = idx >> 6, kk = idx & 63; gw2L[jj * 65 + kk] = gw2[idx]; }
  for (int idx = t; idx < NE * GH;  idx += 256) { int jj = idx >> 6, kk = idx & 63; gw3L[jj * 65 + kk] = gw3[idx]; }
  if (t < GH) { gb1L[t] = gb1[t]; gb2L[t] = gb2[t]; }
  if (t < NE) gb3L[t] = gb3[t];
  if (t < L2W) {
    float m = stats2[t] * (1.f / 1024.f);
    float v = stats2[32 + t] * (1.f / 1024.f) - m * m;
    float sc = gamma2[t] * rsqrtf(v + EPSBN);
    sc2[t] = sc; sh2[t] = beta2[t] - m * sc;
  }
  __syncthreads();
  int wave = t >> 6, l = t & 63;
  int row = blockIdx.x * 4 + wave;
  if (l < L2W) {
    float hv = h2raw[row * L2W + l];
    latb[wave][l] = fmaxf(fmaf(hv, sc2[l], sh2[l]), 0.f);
  }
  __syncthreads();
  float a1 = gb1L[l];
  for (int k = 0; k < L2W; ++k) a1 = fmaf(gw1L[l * 33 + k], latb[wave][k], a1);
  g1b[wave][l] = eluf(a1);
  __syncthreads();
  float a2 = gb2L[l];
  for (int k = 0; k < GH; ++k) a2 = fmaf(gw2L[l * 65 + k], g1b[wave][k], a2);
  g2b[wave][l] = eluf(a2);
  __syncthreads();
  if (l < NE) {
    float a3 = gb3L[l];
    for (int k = 0; k < GH; ++k) a3 = fmaf(gw3L[l * 65 + k], g2b[wave][k], a3);
    lgb[wave][l] = a3;
  }
  __syncthreads();
  if (l < NE) {
    float mx = -1e30f;
    for (int e = 0; e < NE; ++e) mx = fmaxf(mx, lgb[wave][e]);
    float sum = 0.f, mine = 0.f;
    for (int e = 0; e < NE; ++e) {
      float p = expf(lgb[wave][e] - mx);
      if (e == l) mine = p;
      sum += p;
    }
    bc[row * NE + l] = mine / sum;
  }
}

// =============== generator: wave-per-64x64-tile, direct-from-global fragments ===============
// grid (M/256, N/64, 8), block 256 (4 waves); wave w -> mblk = bx*4+w.
// A plane: [64 msub][KC kc][512 sh]; B plane: [8 e][NSUB nsub][KC kc][512 sh].
template<int KC, int NSUB, int LDP>
__global__ __launch_bounds__(256) void genk(const unsigned short* __restrict__ AHp,
    const unsigned short* __restrict__ ALp, const unsigned short* __restrict__ BHp,
    const unsigned short* __restrict__ BLp, float* __restrict__ p) {
  int t = threadIdx.x, w = t >> 6, l = t & 63;
  int mblk = blockIdx.x * 4 + w;
  int nblk = blockIdx.y, e = blockIdx.z;
  const unsigned short* aH = AHp + ((size_t)mblk * 4 * KC) * 512 + l * 8;
  const unsigned short* aL = ALp + ((size_t)mblk * 4 * KC) * 512 + l * 8;
  const unsigned short* bH = BHp + ((size_t)(e * NSUB + nblk * 4) * KC) * 512 + l * 8;
  const unsigned short* bL = BLp + ((size_t)(e * NSUB + nblk * 4) * KC) * 512 + l * 8;
  f32x4 acc[4][4] = {};
  for (int kc = 0; kc < KC; ++kc) {
    bf16x8 AH4[4], AL4[4], BH4[4], BL4[4];
#pragma unroll
    for (int i = 0; i < 4; ++i) {
      AH4[i] = *(const bf16x8*)(aH + (size_t)(i * KC + kc) * 512);
      AL4[i] = *(const bf16x8*)(aL + (size_t)(i * KC + kc) * 512);
      BH4[i] = *(const bf16x8*)(bH + (size_t)(i * KC + kc) * 512);
      BL4[i] = *(const bf16x8*)(bL + (size_t)(i * KC + kc) * 512);
    }
#pragma unroll
    for (int im = 0; im < 4; ++im)
#pragma unroll
      for (int in = 0; in < 4; ++in) {
        acc[im][in] = __builtin_amdgcn_mfma_f32_16x16x32_bf16(AH4[im], BH4[in], acc[im][in], 0, 0, 0);
        acc[im][in] = __builtin_amdgcn_mfma_f32_16x16x32_bf16(AL4[im], BH4[in], acc[im][in], 0, 0, 0);
        acc[im][in] = __builtin_amdgcn_mfma_f32_16x16x32_bf16(AH4[im], BL4[in], acc[im][in], 0, 0, 0);
      }
  }
  int q = l >> 4, c = l & 15;
  float* pe = p + (size_t)e * 1024 * LDP;
#pragma unroll
  for (int im = 0; im < 4; ++im) {
    int m0 = mblk * 64 + im * 16 + q * 4;
#pragma unroll
    for (int in = 0; in < 4; ++in) {
      int col = nblk * 64 + in * 16 + c;
#pragma unroll
      for (int r = 0; r < 4; ++r) pe[(size_t)(m0 + r) * LDP + col] = acc[im][in][r];
    }
  }
}

// =============== combine: a = elu(sum_e bc_e*(p[e]+eb_e)) -> fragment-order planes ===============
// 32768 threads: gid = [64 msub][8 kc][64 l]
__global__ __launch_bounds__(256) void combine12(const float* __restrict__ p,
    const float* __restrict__ bc, const float* __restrict__ eb,
    unsigned short* __restrict__ ah, unsigned short* __restrict__ al) {
  int gid = blockIdx.x * 256 + threadIdx.x;
  int l = gid & 63, kc = (gid >> 6) & 7, msub = gid >> 9;
  int b = msub * 16 + (l & 15);
  int k0 = kc * 32 + (l >> 4) * 8;
  float wv[NE];
#pragma unroll
  for (int e = 0; e < NE; ++e) wv[e] = bc[b * NE + e];
  float s[8] = {};
#pragma unroll
  for (int e = 0; e < NE; ++e) {
    const float* pr = p + ((size_t)e << 18) + (size_t)b * HH + k0;
    float4 p0 = *(const float4*)pr, p1 = *(const float4*)(pr + 4);
    const float* er = eb + e * HH + k0;
    float4 e0 = *(const float4*)er, e1 = *(const float4*)(er + 4);
    s[0] = fmaf(wv[e], p0.x + e0.x, s[0]);
    s[1] = fmaf(wv[e], p0.y + e0.y, s[1]);
    s[2] = fmaf(wv[e], p0.z + e0.z, s[2]);
    s[3] = fmaf(wv[e], p0.w + e0.w, s[3]);
    s[4] = fmaf(wv[e], p1.x + e1.x, s[4]);
    s[5] = fmaf(wv[e], p1.y + e1.y, s[5]);
    s[6] = fmaf(wv[e], p1.z + e1.z, s[6]);
    s[7] = fmaf(wv[e], p1.w + e1.w, s[7]);
  }
  us8 H, L;
#pragma unroll
  for (int j = 0; j < 8; ++j) {
    float v = eluf(s[j]);
    unsigned short h, lo; split_bf16(v, h, lo);
    H[j] = h; L[j] = lo;
  }
  *(us8*)(ah + (size_t)gid * 8) = H;
  *(us8*)(al + (size_t)gid * 8) = L;
}

// =============== combine3: out = sum_e bc_e*(p3[e]+eb3_e) ===============
__global__ __launch_bounds__(256) void combine3(const float* __restrict__ p3,
    const float* __restrict__ bc, const float* __restrict__ eb3, float* __restrict__ out) {
  int gid = blockIdx.x * 256 + threadIdx.x;   // 65536 = 1024 * 64
  int b = gid >> 6, o = gid & 63;
  if (o >= DOUT) return;
  float s = 0.f;
#pragma unroll
  for (int e = 0; e < NE; ++e)
    s = fmaf(bc[b * NE + e], p3[((size_t)e << 16) + (size_t)b * 64 + o] + eb3[e * DOUT + o], s);
  out[(size_t)b * DOUT + o] = s;
}

extern "C" void kernel_launch(void* const* d_in, const int* in_sizes, int n_in,
                              void* d_out, int out_size, void* d_ws, size_t ws_size,
                              hipStream_t stream) {
  const float* x      = (const float*)d_in[0];
  const float* w1     = (const float*)d_in[1];
  const float* b1     = (const float*)d_in[2];
  const float* gamma1 = (const float*)d_in[3];
  const float* beta1  = (const float*)d_in[4];
  const float* w2     = (const float*)d_in[5];
  const float* b2     = (const float*)d_in[6];
  const float* gamma2 = (const float*)d_in[7];
  const float* beta2  = (const float*)d_in[8];
  const float* gw1    = (const float*)d_in[9];
  const float* gb1    = (const float*)d_in[10];
  const float* gw2    = (const float*)d_in[11];
  const float* gb2    = (const float*)d_in[12];
  const float* gw3    = (const float*)d_in[13];
  const float* gb3    = (const float*)d_in[14];
  const float* ew1    = (const float*)d_in[15];
  const float* eb1    = (const float*)d_in[16];
  const float* ew2    = (const float*)d_in[17];
  const float* eb2    = (const float*)d_in[18];
  const float* ew3    = (const float*)d_in[19];
  const float* eb3    = (const float*)d_in[20];

  float* ws    = (float*)d_ws;
  float* h1raw = ws;
  float* h2raw = ws + 65536;
  float* bcp   = ws + 98304;
  float* stats = ws + 106496;
  unsigned short* XsH = (unsigned short*)(ws + 106752);
  unsigned short* XsL = (unsigned short*)(ws + 172288);
  unsigned short* E1H = (unsigned short*)(ws + 237824);
  unsigned short* E1L = (unsigned short*)(ws + 368896);
  unsigned short* E2H = (unsigned short*)(ws + 499968);
  unsigned short* E2L = (unsigned short*)(ws + 762112);
  unsigned short* E3H = (unsigned short*)(ws + 1024256);
  unsigned short* E3L = (unsigned short*)(ws + 1089792);
  unsigned short* AH  = (unsigned short*)(ws + 1155328);
  unsigned short* AL  = (unsigned short*)(ws + 1286400);
  float* p     = ws + 1417472;   // 8 MB partials (also p3)
  float* outp  = (float*)d_out;

  hipMemsetAsync(stats, 0, 192 * sizeof(float), stream);
  prep<<<512, 256, 0, stream>>>(x, ew1, ew2, ew3, XsH, XsL, E1H, E1L, E2H, E2L, E3H, E3L);
  enc_pre<<<256, 256, 0, stream>>>(x, w1, b1, h1raw, stats);
  enc_mid<<<256, 256, 0, stream>>>(h1raw, stats, gamma1, beta1, w2, b2, h2raw, stats + 128);
  gate_kernel<<<256, 256, 0, stream>>>(h2raw, stats + 128, gamma2, beta2,
                                       gw1, gb1, gw2, gb2, gw3, gb3, bcp);
  genk<4, 16, 256><<<dim3(4, 4, 8), 256, 0, stream>>>(XsH, XsL, E1H, E1L, p);
  combine12<<<128, 256, 0, stream>>>(p, bcp, eb1, AH, AL);
  genk<8, 16, 256><<<dim3(4, 4, 8), 256, 0, stream>>>(AH, AL, E2H, E2L, p);
  combine12<<<128, 256, 0, stream>>>(p, bcp, eb2, AH, AL);
  genk<8, 4, 64><<<dim3(4, 1, 8), 256, 0, stream>>>(AH, AL, E3H, E3L, p);
  combine3<<<256, 256, 0, stream>>>(p, bcp, eb3, outp);
}